// Round 8
// baseline (253.355 us; speedup 1.0000x reference)
//
#include <hip/hip_runtime.h>
#include <stddef.h>

// Correlation cost volume via bf16 MFMA band-matmul.
// out[b, di*9+dj, h, w] = (1/256) * sum_c x1[b,c,h,w] * x2[b,c,h+di-4,w+dj-4]
// B=4, C=256, H=96, W=192.
//
// R8 -> R9: R8's VGPR_Count=56 proved the compiler SANK the ping-pong
// B-prefetch (bfr[2][9] alone needs 72 VGPR) down to its uses -> 0-deep
// pipeline -> 104us latency-idle. Fixes:
//  1) __builtin_amdgcn_sched_barrier(0) between next-chunk load issue and
//     the MFMA block: hard fence, loads must be ISSUED before MFMAs ->
//     counted vmcnt(10) (never 0) -> true 1-chunk-deep pipeline.
//     Verify via VGPR_Count >= 100.
//  2) Pack x1 fragment-native too (same transform, no halo): A-frag = one
//     contiguous 16B/lane load; main loop has ZERO f2bf and no scattered
//     gathers -- 10 loads + 9 MFMA + addr bumps per chunk.

#define NB 4
#define NC 256
#define HH 96
#define WW 192
#define TW 16
#define TH 2
#define KC 32
#define CHW (HH * WW)         // 18432

// x2 fragment tiles: [b][hp 0..103][wt 0..12][cg 0..7], 1KB each
#define HP 104
#define WT 13
#define NCG 8
#define TILE_US 512                          // ushorts per tile (1KB)
#define NTILES (NB * HP * WT * NCG)          // 43,264
#define XT2_BYTES ((size_t)NTILES * 1024)    // 44,302,336 B
#define XT2_ELEMS ((size_t)NTILES * TILE_US)
// x1 fragment tiles: [b][h 0..95][wt 0..11][cg 0..7], 1KB each (no pad)
#define WT1 12
#define NT1 (NB * HH * WT1 * NCG)            // 36,864
#define FT1_BYTES ((size_t)NT1 * 1024)       // 37,748,736 B

typedef __attribute__((ext_vector_type(8))) short bf16x8;
typedef __attribute__((ext_vector_type(4))) float f32x4;

__device__ __forceinline__ unsigned short f2bf(float f) {
    union { float f; unsigned u; } c; c.f = f;
    unsigned r = c.u + 0x7FFFu + ((c.u >> 16) & 1u);   // round-to-nearest-even
    return (unsigned short)(r >> 16);
}

// ---------------- pack x2 -> fragment-native bf16 tiles (padded) -----------
__global__ __launch_bounds__(256) void pack_x2(
    const float* __restrict__ x2, unsigned short* __restrict__ ft)
{
    const int wv   = threadIdx.x >> 6;
    const int lane = threadIdx.x & 63;
    const int col  = lane & 15;
    const int q    = lane >> 4;

    const int tid0 = blockIdx.x * 4 + wv;    // tile id 0..43263
    int t = tid0;
    const int cg = t & 7;  t >>= 3;
    const int wt = t % WT; t /= WT;
    const int hp = t % HP;
    const int b  = t / HP;

    const int gh = hp - 4;
    const int gw = wt * 16 + col - 4;
    const bool ok = (gh >= 0) & (gh < HH) & (gw >= 0) & (gw < WW);

    bf16x8 v;
    if (ok) {
        const float* src = &x2[(unsigned)((b * NC + cg * 32 + q * 8) * HH + gh) * WW + gw];
#pragma unroll
        for (int j = 0; j < 8; ++j) v[j] = (short)f2bf(src[(size_t)j * CHW]);
    } else {
#pragma unroll
        for (int j = 0; j < 8; ++j) v[j] = 0;
    }
    *(bf16x8*)&ft[(unsigned)tid0 * TILE_US + lane * 8] = v;
}

// ---------------- pack x1 -> fragment-native bf16 tiles (no pad) -----------
__global__ __launch_bounds__(256) void pack_x1(
    const float* __restrict__ x1, unsigned short* __restrict__ ft1)
{
    const int wv   = threadIdx.x >> 6;
    const int lane = threadIdx.x & 63;
    const int col  = lane & 15;
    const int q    = lane >> 4;

    const int tid0 = blockIdx.x * 4 + wv;    // tile id 0..36863
    int t = tid0;
    const int cg = t & 7;   t >>= 3;
    const int wt = t % WT1; t /= WT1;
    const int h  = t % HH;
    const int b  = t / HH;

    const float* src = &x1[(unsigned)((b * NC + cg * 32 + q * 8) * HH + h) * WW + wt * 16 + col];
    bf16x8 v;
#pragma unroll
    for (int j = 0; j < 8; ++j) v[j] = (short)f2bf(src[(size_t)j * CHW]);
    *(bf16x8*)&ft1[(unsigned)tid0 * TILE_US + lane * 8] = v;
}

// ---------------- main: forced-pipeline band-matmul, both inputs packed ----
__global__ __launch_bounds__(256, 3) void corr_mfma_ff(
    const unsigned short* __restrict__ ft1,
    const unsigned short* __restrict__ ft2,
    float* __restrict__ out)
{
    __shared__ float band[TH][9][9][18];     // 11,664 B, epilogue only

    // XCD-aware swizzle: 2304 blocks, 288 consecutive tiles per XCD.
    const int lin = blockIdx.x;
    const int sw  = (lin & 7) * 288 + (lin >> 3);
    const int b   = sw / 576;
    const int rem = sw - b * 576;
    const int ty  = rem / 12;                // 48 row-pairs
    const int tx  = rem - ty * 12;

    const int tid  = threadIdx.x;
    const int wv   = tid >> 6;               // 4 waves: (r, dig)
    const int lane = tid & 63;
    const int col  = lane & 15;
    const int q    = lane >> 4;
    const int r    = wv >> 1;                // output row within tile (0..1)
    const int dig  = wv & 1;                 // unit group: 9 of 18 units
    const int w0   = tx * TW;
    const int h0   = ty * TH;
    const int h    = h0 + r;

    f32x4 acc[9];
#pragma unroll
    for (int s = 0; s < 9; ++s) acc[s] = (f32x4)0.0f;

    // B-frag offsets (ushorts), one per unit; cg innermost -> += TILE_US/chunk
    unsigned l2[9];
#pragma unroll
    for (int s = 0; s < 9; ++s) {
        const int u  = dig * 9 + s;
        const int di = u >> 1;
        const int uh = u & 1;
        const unsigned tile = (unsigned)(((b * HP + h + di) * WT + (tx + uh)) * NCG);
        l2[s] = tile * TILE_US + lane * 8;
    }
    // A-frag offset: ft1 tile (b, h, tx, cg=chunk)
    unsigned a1 = (unsigned)(((b * HH + h) * WT1 + tx) * NCG) * TILE_US + lane * 8;

    // ---- preload chunk 0
    bf16x8 bfr[2][9];
    bf16x8 av[2];
#pragma unroll
    for (int s = 0; s < 9; ++s) {
        bfr[0][s] = *(const bf16x8*)&ft2[l2[s]];
        l2[s] += TILE_US;
    }
    av[0] = *(const bf16x8*)&ft1[a1]; a1 += TILE_US;

#pragma unroll
    for (int ci = 0; ci < 8; ++ci) {
        const int cur = ci & 1;
        const int nxt = cur ^ 1;
        // issue next chunk's 10 loads FIRST
        if (ci < 7) {
#pragma unroll
            for (int s = 0; s < 9; ++s) {
                bfr[nxt][s] = *(const bf16x8*)&ft2[l2[s]];
                l2[s] += TILE_US;
            }
            av[nxt] = *(const bf16x8*)&ft1[a1]; a1 += TILE_US;
        }
        // HARD fence: loads above may not sink below; MFMAs may not hoist
        // above. Forces true 1-chunk-deep pipeline (counted vmcnt(10), not 0).
        __builtin_amdgcn_sched_barrier(0);
#pragma unroll
        for (int s = 0; s < 9; ++s)
            acc[s] = __builtin_amdgcn_mfma_f32_16x16x32_bf16(av[cur], bfr[cur][s], acc[s], 0, 0, 0);
    }

    // ---- band extraction: P[m, m+dj] -> band[r][di][dj][m]
#pragma unroll
    for (int s = 0; s < 9; ++s) {
        const int u  = dig * 9 + s;
        const int di = u >> 1;
        const int uh = u & 1;
#pragma unroll
        for (int rg = 0; rg < 4; ++rg) {
            int m  = q * 4 + rg;
            int dj = uh * 16 + col - m;
            if (dj >= 0 && dj < 9)
                band[r][di][dj][m] = acc[s][rg];
        }
    }
    __syncthreads();

    // ---- coalesced write-out: 81 channels x 2 rows x 16 w per block
    const float scale = 1.0f / 256.0f;
#pragma unroll
    for (int it = 0; it < 11; ++it) {
        int gi = it * 16 + (tid >> 4);       // gi = combo*2 + row, 162 total
        if (gi < 162) {
            int combo = gi >> 1;
            int row   = gi & 1;
            float v = band[row][combo / 9][combo % 9][tid & 15];
            out[((size_t)((b * 81 + combo) * HH + h0 + row)) * WW + w0 + (tid & 15)] = v * scale;
        }
    }
}

// ---------------- middle path: x2 packed only (R8 + sched_barrier) ---------
__global__ __launch_bounds__(256, 3) void corr_mfma_ft(
    const float* __restrict__ x1,
    const unsigned short* __restrict__ ft,
    float* __restrict__ out)
{
    __shared__ float band[TH][9][9][18];

    const int lin = blockIdx.x;
    const int sw  = (lin & 7) * 288 + (lin >> 3);
    const int b   = sw / 576;
    const int rem = sw - b * 576;
    const int ty  = rem / 12;
    const int tx  = rem - ty * 12;

    const int tid  = threadIdx.x;
    const int wv   = tid >> 6;
    const int lane = tid & 63;
    const int col  = lane & 15;
    const int q    = lane >> 4;
    const int r    = wv >> 1;
    const int dig  = wv & 1;
    const int w0   = tx * TW;
    const int h0   = ty * TH;
    const int h    = h0 + r;

    f32x4 acc[9];
#pragma unroll
    for (int s = 0; s < 9; ++s) acc[s] = (f32x4)0.0f;

    unsigned l2[9];
#pragma unroll
    for (int s = 0; s < 9; ++s) {
        const int u  = dig * 9 + s;
        const int di = u >> 1;
        const int uh = u & 1;
        const unsigned tile = (unsigned)(((b * HP + h + di) * WT + (tx + uh)) * NCG);
        l2[s] = tile * TILE_US + lane * 8;
    }
    unsigned o1 = (unsigned)((b * NC + q * 8) * HH + h) * WW + w0 + col;

    bf16x8 bfr[2][9];
#pragma unroll
    for (int s = 0; s < 9; ++s) {
        bfr[0][s] = *(const bf16x8*)&ft[l2[s]];
        l2[s] += TILE_US;
    }
    float pa[8];
#pragma unroll
    for (int j = 0; j < 8; ++j) pa[j] = x1[o1 + j * CHW];
    o1 += KC * CHW;

#pragma unroll
    for (int ci = 0; ci < 8; ++ci) {
        const int cur = ci & 1;
        const int nxt = cur ^ 1;
        bf16x8 a;
#pragma unroll
        for (int j = 0; j < 8; ++j) a[j] = (short)f2bf(pa[j]);
        if (ci < 7) {
#pragma unroll
            for (int s = 0; s < 9; ++s) {
                bfr[nxt][s] = *(const bf16x8*)&ft[l2[s]];
                l2[s] += TILE_US;
            }
#pragma unroll
            for (int j = 0; j < 8; ++j) pa[j] = x1[o1 + j * CHW];
            o1 += KC * CHW;
        }
        __builtin_amdgcn_sched_barrier(0);
#pragma unroll
        for (int s = 0; s < 9; ++s)
            acc[s] = __builtin_amdgcn_mfma_f32_16x16x32_bf16(a, bfr[cur][s], acc[s], 0, 0, 0);
    }

#pragma unroll
    for (int s = 0; s < 9; ++s) {
        const int u  = dig * 9 + s;
        const int di = u >> 1;
        const int uh = u & 1;
#pragma unroll
        for (int rg = 0; rg < 4; ++rg) {
            int m  = q * 4 + rg;
            int dj = uh * 16 + col - m;
            if (dj >= 0 && dj < 9)
                band[r][di][dj][m] = acc[s][rg];
        }
    }
    __syncthreads();

    const float scale = 1.0f / 256.0f;
#pragma unroll
    for (int it = 0; it < 11; ++it) {
        int gi = it * 16 + (tid >> 4);
        if (gi < 162) {
            int combo = gi >> 1;
            int row   = gi & 1;
            float v = band[row][combo / 9][combo % 9][tid & 15];
            out[((size_t)((b * 81 + combo) * HH + h0 + row)) * WW + w0 + (tid & 15)] = v * scale;
        }
    }
}

// ---------------- fallback (R5 kernel, used when ws_size is too small) -----
#define NROWS 12
#define NTASK 1152
#define KS 264
#define RS 1096
#define KSTRIDE (KC * CHW)
#define XBI(row, kg, n) ((row) * RS + (kg) * KS + (n) * 8)

__global__ __launch_bounds__(512, 4) void corr_mfma_fb(
    const float* __restrict__ x1, const float* __restrict__ x2,
    float* __restrict__ out)
{
    __shared__ union {
        unsigned short xb[NROWS * RS];
        float band[4][9][9][18];
    } lds;

    const int lin = blockIdx.x;
    const int sw  = (lin & 7) * 144 + (lin >> 3);
    const int b   = sw / 288;
    const int t2  = sw - b * 288;
    const int ty  = t2 / 12;
    const int tx  = t2 - ty * 12;

    const int tid  = threadIdx.x;
    const int wv   = tid >> 6;
    const int lane = tid & 63;
    const int col  = lane & 15;
    const int q    = lane >> 4;
    const int r    = wv & 3;
    const int dig  = wv >> 2;
    const int w0   = tx * TW;
    const int h0   = ty * 4;
    const int h    = h0 + r;

    f32x4 acc[9];
#pragma unroll
    for (int s = 0; s < 9; ++s) acc[s] = (f32x4)0.0f;

    unsigned o2k[3];
    int      lofk[3];
    bool     okk[3];
    bool     act[3];
#pragma unroll
    for (int k = 0; k < 3; ++k) {
        const int t   = tid + k * 512;
        act[k] = (t < NTASK);
        const int seg = t % 6;
        const int u   = t / 6;
        const int cp  = u & 15;
        const int row = u >> 4;
        const int gh  = h0 - 4 + row;
        const int gw  = w0 - 4 + seg * 4;
        okk[k] = act[k] & (gh >= 0) & (gh < HH) & (gw >= 0) & (gw <= WW - 4);
        const int ghc = gh < 0 ? 0 : (gh > HH - 1 ? HH - 1 : gh);
        const int gwc = gw < 0 ? 0 : gw;
        const int rwc = row > NROWS - 1 ? NROWS - 1 : row;
        o2k[k]  = (unsigned)(((b * NC + cp * 2) * HH + ghc) * WW + gwc);
        lofk[k] = XBI(rwc, cp >> 2, seg * 4) + (cp & 3) * 2;
    }
    unsigned o1 = (unsigned)(((b * NC + q * 8) * HH + h) * WW + w0 + col);

    float pf[24];
    float pa[8];

#define STAGE_LOAD_FB()                                                  \
    {                                                                    \
        _Pragma("unroll")                                                \
        for (int k = 0; k < 3; ++k) {                                    \
            _Pragma("unroll")                                            \
            for (int e = 0; e < 2; ++e) {                                \
                float4 ld = make_float4(0.f, 0.f, 0.f, 0.f);             \
                if (okk[k]) ld = *(const float4*)&x2[o2k[k] + e * CHW];  \
                *(float4*)&pf[(k * 2 + e) * 4] = ld;                     \
            }                                                            \
            o2k[k] += KSTRIDE;                                           \
        }                                                                \
    }

#define X1_LOAD_FB()                                                     \
    {                                                                    \
        _Pragma("unroll")                                                \
        for (int j = 0; j < 8; ++j) pa[j] = x1[o1 + j * CHW];            \
        o1 += KSTRIDE;                                                   \
    }

    STAGE_LOAD_FB();
    X1_LOAD_FB();

    const int rbase = XBI(r, q, col);

    for (int ci = 0; ci < 8; ++ci) {
#pragma unroll
        for (int k = 0; k < 3; ++k) {
            if (act[k]) {
#pragma unroll
                for (int p = 0; p < 4; ++p) {
                    ushort2 v;
                    v.x = f2bf(pf[(k * 2 + 0) * 4 + p]);
                    v.y = f2bf(pf[(k * 2 + 1) * 4 + p]);
                    *(ushort2*)&lds.xb[lofk[k] + p * 8] = v;
                }
            }
        }
        __syncthreads();

        bf16x8 a;
#pragma unroll
        for (int j = 0; j < 8; ++j) a[j] = (short)f2bf(pa[j]);
        if (ci < 7) {
            STAGE_LOAD_FB();
            X1_LOAD_FB();
        }

#pragma unroll
        for (int s = 0; s < 9; ++s) {
            const int u    = dig * 9 + s;
            const int di   = u >> 1;
            const int half = u & 1;
            bf16x8 bb = *(const bf16x8*)&lds.xb[rbase + di * RS + half * 128];
            acc[s] = __builtin_amdgcn_mfma_f32_16x16x32_bf16(a, bb, acc[s], 0, 0, 0);
        }
        __syncthreads();
    }

#pragma unroll
    for (int s = 0; s < 9; ++s) {
        const int u  = dig * 9 + s;
        const int di = u >> 1;
        const int uh = u & 1;
#pragma unroll
        for (int rg = 0; rg < 4; ++rg) {
            int m  = q * 4 + rg;
            int dj = uh * 16 + col - m;
            if (dj >= 0 && dj < 9)
                lds.band[r][di][dj][m] = acc[s][rg];
        }
    }
    __syncthreads();

    const float scale = 1.0f / 256.0f;
#pragma unroll
    for (int it = 0; it < 11; ++it) {
        int gi = it * 32 + (tid >> 4);
        if (gi < 324) {
            int combo = gi >> 2;
            int row   = gi & 3;
            float v = lds.band[row][combo / 9][combo % 9][tid & 15];
            out[((size_t)((b * 81 + combo) * HH + h0 + row)) * WW + w0 + (tid & 15)] = v * scale;
        }
    }
}

extern "C" void kernel_launch(void* const* d_in, const int* in_sizes, int n_in,
                              void* d_out, int out_size, void* d_ws, size_t ws_size,
                              hipStream_t stream) {
    const float* x1 = (const float*)d_in[0];
    const float* x2 = (const float*)d_in[1];
    float* out = (float*)d_out;

    if (ws_size >= XT2_BYTES + FT1_BYTES) {
        unsigned short* ft2 = (unsigned short*)d_ws;
        unsigned short* ft1 = ft2 + XT2_ELEMS;
        pack_x2<<<dim3(NTILES / 4), 256, 0, stream>>>(x2, ft2);
        pack_x1<<<dim3(NT1 / 4), 256, 0, stream>>>(x1, ft1);
        corr_mfma_ff<<<dim3(2304), 256, 0, stream>>>(ft1, ft2, out);
    } else if (ws_size >= XT2_BYTES) {
        unsigned short* ft2 = (unsigned short*)d_ws;
        pack_x2<<<dim3(NTILES / 4), 256, 0, stream>>>(x2, ft2);
        corr_mfma_ft<<<dim3(2304), 256, 0, stream>>>(x1, ft2, out);
    } else {
        corr_mfma_fb<<<dim3(1152), 512, 0, stream>>>(x1, x2, out);
    }
}

// Round 9
// 217.826 us; speedup vs baseline: 1.1631x; 1.1631x over previous
//
#include <hip/hip_runtime.h>
#include <stddef.h>

// Correlation cost volume via bf16 MFMA band-matmul.
// out[b, di*9+dj, h, w] = (1/256) * sum_c x1[b,c,h,w] * x2[b,c,h+di-4,w+dj-4]
// B=4, C=256, H=96, W=192.
//
// R9 -> R10: R9's main kernel (70us) pulled every B-frag through L2 per-wave:
// 16x load amplification (737 MB loaded / 44 MB unique), everything <=26%
// busy. pack_x1 cost 37us to save ~10 (dropped). The ft2 fragment-native
// tiles are contiguous 1KB in exact lane order = exactly global_load_lds's
// required layout (wave-uniform LDS base + lane*16B). New main kernel:
//  - TH=4, 8 waves; per chunk stage 24 tiles (12 rows x 2 wt) = 24 KB into
//    double-buffered LDS via 3 global_load_lds/wave (no VGPR round-trip).
//  - Counted vmcnt(8) + raw s_barrier per chunk (A-loads never drained);
//    sched_barrier fences pin issue order (R9's VGPR=84 proved they work).
//  - Frag reads = conflict-free contiguous ds_read_b128 (~120cy, reused 8x
//    per staged tile across waves).

#define NB 4
#define NC 256
#define HH 96
#define WW 192
#define TW 16
#define KC 32
#define CHW (HH * WW)         // 18432

// x2 fragment tiles: [b][hp 0..103][wt 0..12][cg 0..7], 1KB each
#define HP 104
#define WT 13
#define NCG 8
#define TILE_US 512                          // ushorts per tile (1KB)
#define NTILES (NB * HP * WT * NCG)          // 43,264
#define XT2_BYTES ((size_t)NTILES * 1024)    // 44,302,336 B

typedef __attribute__((ext_vector_type(8))) short bf16x8;
typedef __attribute__((ext_vector_type(4))) float f32x4;

typedef const __attribute__((address_space(1))) void g1void;
typedef __attribute__((address_space(3))) void l3void;

__device__ __forceinline__ unsigned short f2bf(float f) {
    union { float f; unsigned u; } c; c.f = f;
    unsigned r = c.u + 0x7FFFu + ((c.u >> 16) & 1u);   // round-to-nearest-even
    return (unsigned short)(r >> 16);
}

// ---------------- pack x2 -> fragment-native bf16 tiles (padded) -----------
__global__ __launch_bounds__(256) void pack_x2(
    const float* __restrict__ x2, unsigned short* __restrict__ ft)
{
    const int wv   = threadIdx.x >> 6;
    const int lane = threadIdx.x & 63;
    const int col  = lane & 15;
    const int q    = lane >> 4;

    const int tid0 = blockIdx.x * 4 + wv;    // tile id 0..43263
    int t = tid0;
    const int cg = t & 7;  t >>= 3;
    const int wt = t % WT; t /= WT;
    const int hp = t % HP;
    const int b  = t / HP;

    const int gh = hp - 4;
    const int gw = wt * 16 + col - 4;
    const bool ok = (gh >= 0) & (gh < HH) & (gw >= 0) & (gw < WW);

    bf16x8 v;
    if (ok) {
        const float* src = &x2[(unsigned)((b * NC + cg * 32 + q * 8) * HH + gh) * WW + gw];
#pragma unroll
        for (int j = 0; j < 8; ++j) v[j] = (short)f2bf(src[(size_t)j * CHW]);
    } else {
#pragma unroll
        for (int j = 0; j < 8; ++j) v[j] = 0;
    }
    *(bf16x8*)&ft[(unsigned)tid0 * TILE_US + lane * 8] = v;
}

// ---------------- main: LDS-staged band-matmul (global_load_lds) -----------
__global__ __launch_bounds__(512, 4) void corr_mfma_lds(
    const float* __restrict__ x1,
    const unsigned short* __restrict__ ft2,
    float* __restrict__ out)
{
    __shared__ union {
        unsigned short stage[2][24][TILE_US];   // 49,152 B: dbuf x 24 tiles
        float band[4][9][9][18];                // 23,328 B: epilogue staging
    } lds;

    // XCD-aware swizzle: 1152 blocks, 144 consecutive tiles per XCD.
    const int lin = blockIdx.x;
    const int sw  = (lin & 7) * 144 + (lin >> 3);
    const int b   = sw / 288;
    const int t2  = sw - b * 288;
    const int ty  = t2 / 12;                 // 24 row-quads
    const int tx  = t2 - ty * 12;

    const int tid  = threadIdx.x;
    const int wv   = tid >> 6;               // 8 waves: (r, dig)
    const int lane = tid & 63;
    const int col  = lane & 15;              // MFMA m/n 16-index
    const int q    = lane >> 4;              // MFMA k-quad
    const int r    = wv & 3;                 // output row within tile
    const int dig  = wv >> 2;                // unit group: 9 of 18 units
    const int w0   = tx * TW;
    const int h0   = ty * 4;
    const int h    = h0 + r;

    f32x4 acc[9];
#pragma unroll
    for (int s = 0; s < 9; ++s) acc[s] = (f32x4)0.0f;

    // ---- stage tasks: 24 tiles (row 0..11 x uh 0..1), 3 per wave.
    // go[k] = ft2 elem offset (cg innermost -> += TILE_US per chunk);
    // LDS dest = stage[buf][t][0] + lane*16B (implicit in global_load_lds).
    unsigned go[3];
    int      tl[3];
#pragma unroll
    for (int k = 0; k < 3; ++k) {
        const int t   = wv * 3 + k;
        const int row = t >> 1;
        const int uh  = t & 1;
        tl[k] = t;
        go[k] = (unsigned)(((b * HP + h0 + row) * WT + tx + uh) * NCG) * TILE_US
              + lane * 8;
    }
    unsigned o1 = (unsigned)((b * NC + q * 8) * HH + h) * WW + w0 + col;

#define STAGE(nb_)                                                            \
    {                                                                         \
        _Pragma("unroll")                                                     \
        for (int k = 0; k < 3; ++k) {                                         \
            __builtin_amdgcn_global_load_lds(                                 \
                (g1void*)(ft2 + go[k]),                                       \
                (l3void*)&lds.stage[nb_][tl[k]][0], 16, 0, 0);                \
            go[k] += TILE_US;                                                 \
        }                                                                     \
    }

    float pa[8];

    // ---- prologue: stage chunk 0 -> buf0, gather A(0); drain stages only.
    STAGE(0);
#pragma unroll
    for (int j = 0; j < 8; ++j) pa[j] = x1[o1 + j * CHW];
    o1 += KC * CHW;
    asm volatile("s_waitcnt vmcnt(8)" ::: "memory");   // 3 stages done; 8 A fly
    __builtin_amdgcn_sched_barrier(0);
    __builtin_amdgcn_s_barrier();
    __builtin_amdgcn_sched_barrier(0);

#pragma unroll
    for (int ci = 0; ci < 8; ++ci) {
        const int cur = ci & 1;
        const int nxt = cur ^ 1;

        // (1) issue next chunk's async stages first: fly across pack+MFMA
        if (ci < 7) STAGE(nxt);
        __builtin_amdgcn_sched_barrier(0);

        // (2) pack A(ci) (compiler emits counted vmcnt: 3 stages younger)
        bf16x8 a;
#pragma unroll
        for (int j = 0; j < 8; ++j) a[j] = (short)f2bf(pa[j]);
        // (3) gather A(ci+1) into pa (WAR ok: a consumed pa)
        if (ci < 7) {
#pragma unroll
            for (int j = 0; j < 8; ++j) pa[j] = x1[o1 + j * CHW];
            o1 += KC * CHW;
        }

        // (4) frags from buf[cur] (contiguous 1KB ds_read_b128, no conflicts)
#pragma unroll
        for (int s = 0; s < 9; ++s) {
            const int u  = dig * 9 + s;
            const int di = u >> 1;
            const int uh = u & 1;
            const bf16x8 bb =
                *(const bf16x8*)&lds.stage[cur][(r + di) * 2 + uh][lane * 8];
            acc[s] = __builtin_amdgcn_mfma_f32_16x16x32_bf16(a, bb, acc[s], 0, 0, 0);
        }

        // (5) chunk boundary: wait own 3 stage-writes (8 A-loads keep flying),
        // then barrier -> buf[nxt] complete for all waves.
        if (ci < 7) {
            asm volatile("s_waitcnt vmcnt(8)" ::: "memory");
            __builtin_amdgcn_sched_barrier(0);
            __builtin_amdgcn_s_barrier();
            __builtin_amdgcn_sched_barrier(0);
        }
    }

    __syncthreads();   // all frag reads done before band overwrites the union

    // ---- band extraction: P[m, m+dj] -> band[r][di][dj][m]
    // D layout: col = lane&15 (=n), row m = q*4 + reg.
#pragma unroll
    for (int s = 0; s < 9; ++s) {
        const int u  = dig * 9 + s;
        const int di = u >> 1;
        const int uh = u & 1;
#pragma unroll
        for (int rg = 0; rg < 4; ++rg) {
            int m  = q * 4 + rg;
            int dj = uh * 16 + col - m;
            if (dj >= 0 && dj < 9)
                lds.band[r][di][dj][m] = acc[s][rg];
        }
    }
    __syncthreads();

    // ---- coalesced write-out: 81 channels x 4 rows x 16 w per block
    const float scale = 1.0f / 256.0f;
#pragma unroll
    for (int it = 0; it < 11; ++it) {
        int gi = it * 32 + (tid >> 4);       // gi = combo*4 + row, 324 total
        if (gi < 324) {
            int combo = gi >> 2;
            int row   = gi & 3;
            float v = lds.band[row][combo / 9][combo % 9][tid & 15];
            out[((size_t)((b * 81 + combo) * HH + h0 + row)) * WW + w0 + (tid & 15)] = v * scale;
        }
    }
}

// ---------------- fallback (R5 kernel, used when ws_size is too small) -----
#define NROWS 12
#define NTASK 1152
#define KS 264
#define RS 1096
#define KSTRIDE (KC * CHW)
#define XBI(row, kg, n) ((row) * RS + (kg) * KS + (n) * 8)

__global__ __launch_bounds__(512, 4) void corr_mfma_fb(
    const float* __restrict__ x1, const float* __restrict__ x2,
    float* __restrict__ out)
{
    __shared__ union {
        unsigned short xb[NROWS * RS];
        float band[4][9][9][18];
    } lds;

    const int lin = blockIdx.x;
    const int sw  = (lin & 7) * 144 + (lin >> 3);
    const int b   = sw / 288;
    const int t2  = sw - b * 288;
    const int ty  = t2 / 12;
    const int tx  = t2 - ty * 12;

    const int tid  = threadIdx.x;
    const int wv   = tid >> 6;
    const int lane = tid & 63;
    const int col  = lane & 15;
    const int q    = lane >> 4;
    const int r    = wv & 3;
    const int dig  = wv >> 2;
    const int w0   = tx * TW;
    const int h0   = ty * 4;
    const int h    = h0 + r;

    f32x4 acc[9];
#pragma unroll
    for (int s = 0; s < 9; ++s) acc[s] = (f32x4)0.0f;

    unsigned o2k[3];
    int      lofk[3];
    bool     okk[3];
    bool     act[3];
#pragma unroll
    for (int k = 0; k < 3; ++k) {
        const int t   = tid + k * 512;
        act[k] = (t < NTASK);
        const int seg = t % 6;
        const int u   = t / 6;
        const int cp  = u & 15;
        const int row = u >> 4;
        const int gh  = h0 - 4 + row;
        const int gw  = w0 - 4 + seg * 4;
        okk[k] = act[k] & (gh >= 0) & (gh < HH) & (gw >= 0) & (gw <= WW - 4);
        const int ghc = gh < 0 ? 0 : (gh > HH - 1 ? HH - 1 : gh);
        const int gwc = gw < 0 ? 0 : gw;
        const int rwc = row > NROWS - 1 ? NROWS - 1 : row;
        o2k[k]  = (unsigned)(((b * NC + cp * 2) * HH + ghc) * WW + gwc);
        lofk[k] = XBI(rwc, cp >> 2, seg * 4) + (cp & 3) * 2;
    }
    unsigned o1 = (unsigned)(((b * NC + q * 8) * HH + h) * WW + w0 + col);

    float pf[24];
    float pa[8];

#define STAGE_LOAD_FB()                                                  \
    {                                                                    \
        _Pragma("unroll")                                                \
        for (int k = 0; k < 3; ++k) {                                    \
            _Pragma("unroll")                                            \
            for (int e = 0; e < 2; ++e) {                                \
                float4 ld = make_float4(0.f, 0.f, 0.f, 0.f);             \
                if (okk[k]) ld = *(const float4*)&x2[o2k[k] + e * CHW];  \
                *(float4*)&pf[(k * 2 + e) * 4] = ld;                     \
            }                                                            \
            o2k[k] += KSTRIDE;                                           \
        }                                                                \
    }

#define X1_LOAD_FB()                                                     \
    {                                                                    \
        _Pragma("unroll")                                                \
        for (int j = 0; j < 8; ++j) pa[j] = x1[o1 + j * CHW];            \
        o1 += KSTRIDE;                                                   \
    }

    STAGE_LOAD_FB();
    X1_LOAD_FB();

    const int rbase = XBI(r, q, col);

    for (int ci = 0; ci < 8; ++ci) {
#pragma unroll
        for (int k = 0; k < 3; ++k) {
            if (act[k]) {
#pragma unroll
                for (int p = 0; p < 4; ++p) {
                    ushort2 v;
                    v.x = f2bf(pf[(k * 2 + 0) * 4 + p]);
                    v.y = f2bf(pf[(k * 2 + 1) * 4 + p]);
                    *(ushort2*)&lds.xb[lofk[k] + p * 8] = v;
                }
            }
        }
        __syncthreads();

        bf16x8 a;
#pragma unroll
        for (int j = 0; j < 8; ++j) a[j] = (short)f2bf(pa[j]);
        if (ci < 7) {
            STAGE_LOAD_FB();
            X1_LOAD_FB();
        }

#pragma unroll
        for (int s = 0; s < 9; ++s) {
            const int u    = dig * 9 + s;
            const int di   = u >> 1;
            const int half = u & 1;
            bf16x8 bb = *(const bf16x8*)&lds.xb[rbase + di * RS + half * 128];
            acc[s] = __builtin_amdgcn_mfma_f32_16x16x32_bf16(a, bb, acc[s], 0, 0, 0);
        }
        __syncthreads();
    }

#pragma unroll
    for (int s = 0; s < 9; ++s) {
        const int u  = dig * 9 + s;
        const int di = u >> 1;
        const int uh = u & 1;
#pragma unroll
        for (int rg = 0; rg < 4; ++rg) {
            int m  = q * 4 + rg;
            int dj = uh * 16 + col - m;
            if (dj >= 0 && dj < 9)
                lds.band[r][di][dj][m] = acc[s][rg];
        }
    }
    __syncthreads();

    const float scale = 1.0f / 256.0f;
#pragma unroll
    for (int it = 0; it < 11; ++it) {
        int gi = it * 32 + (tid >> 4);
        if (gi < 324) {
            int combo = gi >> 2;
            int row   = gi & 3;
            float v = lds.band[row][combo / 9][combo % 9][tid & 15];
            out[((size_t)((b * 81 + combo) * HH + h0 + row)) * WW + w0 + (tid & 15)] = v * scale;
        }
    }
}

extern "C" void kernel_launch(void* const* d_in, const int* in_sizes, int n_in,
                              void* d_out, int out_size, void* d_ws, size_t ws_size,
                              hipStream_t stream) {
    const float* x1 = (const float*)d_in[0];
    const float* x2 = (const float*)d_in[1];
    float* out = (float*)d_out;

    if (ws_size >= XT2_BYTES) {
        unsigned short* ft2 = (unsigned short*)d_ws;
        pack_x2<<<dim3(NTILES / 4), 256, 0, stream>>>(x2, ft2);
        corr_mfma_lds<<<dim3(1152), 512, 0, stream>>>(x1, ft2, out);
    } else {
        corr_mfma_fb<<<dim3(1152), 512, 0, stream>>>(x1, x2, out);
    }
}